// Round 12
// baseline (910.721 us; speedup 1.0000x reference)
//
#include <hip/hip_runtime.h>
#include <cstdint>
#include <cstddef>

// ---------------------------------------------------------------------------
// AttnCodebook on MI355X (gfx950). Round 12:
//  - gemm8p / gemm_n384 reverted to round-8 4-phase versions (841 us best)
//  - NEW gemm_ff13L: 256-thread, 48 KB LDS (3 blocks/CU -> 3 waves/SIMD of
//    independent work), 128x128 dual-output tile, BK=32 double-buffer,
//    2 barriers/K-tile, counted vmcnt(6). Tests the occupancy/latency theory
//    from round-11 counters (MfmaUtil 23 / VALU 18 / Occ 23 = latency-bound).
// ---------------------------------------------------------------------------

typedef __bf16 bf16_t;
typedef __bf16 bf16x8 __attribute__((ext_vector_type(8)));
typedef float  f32x4  __attribute__((ext_vector_type(4)));
typedef float  f32x16 __attribute__((ext_vector_type(16)));

#define B_    8
#define N_    2048
#define D_    768
#define C_    2048
#define H_    3072
#define NROWS 16384   // B_*N_

// weight bf16 arena (element offsets)
#define WQ_OFF 0
#define WK_OFF 589824
#define WV_OFF 1179648
#define WC_OFF 1769472
#define W1_OFF 2359296
#define W3_OFF 4718592
#define W2_OFF 7077888
#define WTOT   9437184

// ---- d_ws layout (bytes). ws_size ~1.8 GB.
#define WS_W     0ull
#define WS_TRIG  18874368ull
#define WS_VCT   25165824ull   // bf16 vcT [768][2048]
#define WS_NC    28311552ull   // bf16 normed_context [2048][768]
#define WS_NQ    31457280ull   // bf16 normed_queries
#define WS_Z     56623104ull   // bf16 z [16384][2048]
#define WS_H     28311552ull   // bf16 h (reuse NC/NQ region, live P7-P8)
#define WS_G     157286400ull  // bf16 g [16384][3072]
#define WS_VB    257949696ull  // bf16 v [2048][768]

// ---- d_out layout: [cb][la][lat][z]
#define DO_CB    0ull
#define DO_LA    50331648ull
#define DO_LAT   184549376ull
#define DO_Z     318767104ull
// scratch parked in LAT section (dead before lat written); bf16 bases
#define DO_QBASE 184549376ull
#define DO_KBASE (184549376ull + 50331648ull)
#define DO_QROPE (234881024ull + 6291456ull)
#define DO_KROPE (241172480ull + 25165824ull)

// ---------------------------------------------------------------------------
__device__ __forceinline__ void gl_lds16(const void* g, void* l) {
  __builtin_amdgcn_global_load_lds((__attribute__((address_space(1))) void*)(g),
                                   (__attribute__((address_space(3))) void*)(l),
                                   16, 0, 0);
}

__device__ __forceinline__ void block_sync() {
  __builtin_amdgcn_sched_barrier(0);
  asm volatile("" ::: "memory");
  __builtin_amdgcn_s_barrier();
  asm volatile("" ::: "memory");
  __builtin_amdgcn_sched_barrier(0);
}

__device__ __forceinline__ uint32_t rotl32(uint32_t v, int d) {
  return (v << d) | (v >> (32 - d));
}
__device__ __forceinline__ void tf_round(uint32_t& x0, uint32_t& x1, int r) {
  x0 += x1; x1 = rotl32(x1, r); x1 ^= x0;
}
__device__ __forceinline__ uint2 threefry2x32(uint32_t k0, uint32_t k1,
                                              uint32_t x0, uint32_t x1) {
  const uint32_t k2 = k0 ^ k1 ^ 0x1BD11BDAu;
  x0 += k0; x1 += k1;
  tf_round(x0,x1,13); tf_round(x0,x1,15); tf_round(x0,x1,26); tf_round(x0,x1,6);
  x0 += k1; x1 += k2 + 1u;
  tf_round(x0,x1,17); tf_round(x0,x1,29); tf_round(x0,x1,16); tf_round(x0,x1,24);
  x0 += k2; x1 += k0 + 2u;
  tf_round(x0,x1,13); tf_round(x0,x1,15); tf_round(x0,x1,26); tf_round(x0,x1,6);
  x0 += k0; x1 += k1 + 3u;
  tf_round(x0,x1,17); tf_round(x0,x1,29); tf_round(x0,x1,16); tf_round(x0,x1,24);
  x0 += k1; x1 += k2 + 4u;
  tf_round(x0,x1,13); tf_round(x0,x1,15); tf_round(x0,x1,26); tf_round(x0,x1,6);
  x0 += k2; x1 += k0 + 5u;
  return make_uint2(x0, x1);
}

#define SWZ(o) ((o) ^ ((((o) >> 7) & 3) << 4))

#define PHASE_MFMA_OPEN() do { \
    block_sync(); \
    asm volatile("s_waitcnt lgkmcnt(0)" ::: "memory"); \
    __builtin_amdgcn_sched_barrier(0); \
    __builtin_amdgcn_s_setprio(1); \
  } while (0)
#define PHASE_MFMA_CLOSE() do { \
    __builtin_amdgcn_s_setprio(0); \
    __builtin_amdgcn_sched_barrier(0); \
  } while (0)

// C/D 32x32 map: col = lane&31, row = (reg&3) + 8*(reg>>2) + 4*(lane>>5)
#define ROWMAP32(rg, kg) (((rg) & 3) + 8 * ((rg) >> 2) + 4 * (kg))

// ---------------------------------------------------------------------------
// 256x256 8-wave 4-phase GEMM, 32x32x16 MFMA. (qk) -- round-8 version
// ---------------------------------------------------------------------------
template <int EPI>
__global__ __launch_bounds__(512, 2) void gemm8p(
    const bf16_t* __restrict__ A, const bf16_t* __restrict__ B,
    void* outp, const void* auxp, const float* sptr,
    int M, int N, int K, long sA, long sB, long sO)
{
  __shared__ bf16_t As[2][2][8192];
  __shared__ bf16_t Bs[2][2][8192];
  const int tid  = threadIdx.x;
  const int lane = tid & 63;
  const int wid  = tid >> 6;
  const int wm = wid >> 2, wn = wid & 3;
  const int l31 = lane & 31, kg = lane >> 5;

  const int lin = (blockIdx.z * gridDim.y + blockIdx.y) * gridDim.x + blockIdx.x;
  const int swzb = (lin & 7) * 64 + (lin >> 3);
  const int bz = swzb >> 6;
  const int ny = (swzb & 63) >> 3;
  const int nx = swzb & 7;

  const bf16_t* Ab = A + (size_t)bz * (size_t)sA;
  const bf16_t* Bb = B + (size_t)bz * (size_t)sB;
  const int tm = ny * 256;
  const int tn = nx * 256;
  const int nt = K >> 6;

  const bf16_t *srcA0, *srcA1, *srcB0, *srcB1;
  {
    const int d0 = wid * 1024 + lane * 16;
    const int p0 = SWZ(d0);
    srcA0 = Ab + (size_t)(tm + (p0 >> 6)) * K + ((p0 & 63) >> 1);
    srcB0 = Bb + (size_t)(tn + (p0 >> 6)) * K + ((p0 & 63) >> 1);
    const int d1 = 8192 + wid * 1024 + lane * 16;
    const int p1 = SWZ(d1);
    srcA1 = Ab + (size_t)(tm + (p1 >> 6)) * K + ((p1 & 63) >> 1);
    srcB1 = Bb + (size_t)(tn + (p1 >> 6)) * K + ((p1 & 63) >> 1);
  }
  bf16_t* dstA = &As[0][0][0] + wid * 512;
  bf16_t* dstB = &Bs[0][0][0] + wid * 512;

  int olA[4][2], olB[2][2];
  #pragma unroll
  for (int mb = 0; mb < 4; ++mb)
    #pragma unroll
    for (int u = 0; u < 2; ++u) {
      const int o = ((wm * 128 + mb * 32 + l31) << 6) + u * 32 + (kg << 4);
      olA[mb][u] = SWZ(o);
    }
  #pragma unroll
  for (int nb = 0; nb < 2; ++nb)
    #pragma unroll
    for (int u = 0; u < 2; ++u) {
      const int o = ((wn * 64 + nb * 32 + l31) << 6) + u * 32 + (kg << 4);
      olB[nb][u] = SWZ(o);
    }

#define STG_A(tile_, kk_) do { \
    const size_t ko_ = (size_t)(tile_) * 64 + (size_t)(kk_) * 32; \
    bf16_t* db_ = dstA + (((tile_) & 1) ? 16384 : 0) + ((kk_) ? 8192 : 0); \
    gl_lds16(srcA0 + ko_, db_); \
    gl_lds16(srcA1 + ko_, db_ + 4096); \
  } while (0)
#define STG_B(tile_, kk_) do { \
    const size_t ko_ = (size_t)(tile_) * 64 + (size_t)(kk_) * 32; \
    bf16_t* db_ = dstB + (((tile_) & 1) ? 16384 : 0) + ((kk_) ? 8192 : 0); \
    gl_lds16(srcB0 + ko_, db_); \
    gl_lds16(srcB1 + ko_, db_ + 4096); \
  } while (0)

  f32x16 acc[4][2] = {};

  STG_A(0, 0); STG_B(0, 0); STG_A(0, 1); STG_B(0, 1);
  STG_B(1, 0); STG_A(1, 0); STG_B(1, 1);
  asm volatile("s_waitcnt vmcnt(6)" ::: "memory");
  block_sync();

  for (int t = 0; t < nt; ++t) {
    const int s = t & 1;
    bf16x8 bfr[2][2];
    #pragma unroll
    for (int q = 0; q < 4; ++q) {
      const int kk = q >> 1, mh = q & 1;
      if (q == 0)      { if (t + 1 < nt) STG_A(t + 1, 1); }
      else if (q == 1) { if (t + 2 < nt) STG_B(t + 2, 0); }
      else if (q == 2) { if (t + 2 < nt) STG_A(t + 2, 0); }
      else             { if (t + 2 < nt) STG_B(t + 2, 1); }
      if (mh == 0) {
        const char* Bbase = (const char*)&Bs[s][kk][0];
        #pragma unroll
        for (int nb = 0; nb < 2; ++nb)
          #pragma unroll
          for (int u = 0; u < 2; ++u)
            bfr[nb][u] = *(const bf16x8*)(Bbase + olB[nb][u]);
      }
      const char* Abase = (const char*)&As[s][kk][0];
      bf16x8 af[2][2];
      #pragma unroll
      for (int j = 0; j < 2; ++j)
        #pragma unroll
        for (int u = 0; u < 2; ++u)
          af[j][u] = *(const bf16x8*)(Abase + olA[mh * 2 + j][u]);
      PHASE_MFMA_OPEN();
      #pragma unroll
      for (int u = 0; u < 2; ++u)
        #pragma unroll
        for (int j = 0; j < 2; ++j)
          #pragma unroll
          for (int nb = 0; nb < 2; ++nb)
            acc[mh * 2 + j][nb] =
              __builtin_amdgcn_mfma_f32_32x32x16_bf16(af[j][u], bfr[nb][u], acc[mh * 2 + j][nb], 0, 0, 0);
      PHASE_MFMA_CLOSE();
      if (q == 3) asm volatile("s_waitcnt vmcnt(6)" ::: "memory");
      block_sync();
    }
  }
#undef STG_A
#undef STG_B

  #pragma unroll
  for (int mb = 0; mb < 4; ++mb) {
    #pragma unroll
    for (int nb = 0; nb < 2; ++nb) {
      const int cg = tn + wn * 64 + nb * 32 + l31;
      #pragma unroll
      for (int rg = 0; rg < 16; ++rg) {
        const int r = tm + wm * 128 + mb * 32 + ROWMAP32(rg, kg);
        const float v = acc[mb][nb][rg];
        const size_t idx = (size_t)r * N + cg;
        if (EPI == 1) {
          ((float*)outp)[(size_t)bz * sO + idx] = v * 0.03608439182435161f; // 1/sqrt(768)
        } else {
          ((float*)outp)[(size_t)bz * sO + idx] = v;
        }
      }
    }
  }
}

// ---------------------------------------------------------------------------
// BM=128 x BN=384 8-wave 4-phase GEMM, 32x32x16 MFMA. grid (2, 128).
// EPI: 2=bf16  5=f32 s*aux+acc  6=f32 aux+acc  -- round-8 version
// ---------------------------------------------------------------------------
template <int EPI>
__global__ __launch_bounds__(512, 2) void gemm_n384(
    const bf16_t* __restrict__ A, const bf16_t* __restrict__ B,
    void* outp, const void* auxp, const float* sptr, int K)
{
  __shared__ bf16_t As[2][2][4096];
  __shared__ bf16_t Bs[2][2][12288];
  const int tid  = threadIdx.x;
  const int lane = tid & 63;
  const int wid  = tid >> 6;
  const int wm = wid >> 2, wn = wid & 3;
  const int l31 = lane & 31, kg = lane >> 5;

  const int lin = blockIdx.y * 2 + blockIdx.x;
  const int swzb = (lin & 7) * 32 + (lin >> 3);
  const int ny = swzb >> 1;
  const int nx = swzb & 1;

  const int tm = ny * 128;
  const int tn = nx * 384;
  const int nt = K >> 6;

  const bf16_t *srcA, *srcB0, *srcB1, *srcB2;
  {
    const int d = wid * 1024 + lane * 16;
    const int p = SWZ(d);
    srcA = A + (size_t)(tm + (p >> 6)) * K + ((p & 63) >> 1);
    srcB0 = B + (size_t)(tn + (p >> 6)) * K + ((p & 63) >> 1);
    const int d1 = 8192 + d, p1 = SWZ(d1);
    srcB1 = B + (size_t)(tn + (p1 >> 6)) * K + ((p1 & 63) >> 1);
    const int d2 = 16384 + d, p2 = SWZ(d2);
    srcB2 = B + (size_t)(tn + (p2 >> 6)) * K + ((p2 & 63) >> 1);
  }
  bf16_t* dstA = &As[0][0][0] + wid * 512;
  bf16_t* dstB = &Bs[0][0][0] + wid * 512;

  int olA[2][2], olB[3][2];
  #pragma unroll
  for (int mb = 0; mb < 2; ++mb)
    #pragma unroll
    for (int u = 0; u < 2; ++u) {
      const int o = ((wm * 64 + mb * 32 + l31) << 6) + u * 32 + (kg << 4);
      olA[mb][u] = SWZ(o);
    }
  #pragma unroll
  for (int nb = 0; nb < 3; ++nb)
    #pragma unroll
    for (int u = 0; u < 2; ++u) {
      const int o = ((wn * 96 + nb * 32 + l31) << 6) + u * 32 + (kg << 4);
      olB[nb][u] = SWZ(o);
    }

#define STG_A(tile_, kk_) do { \
    const size_t ko_ = (size_t)(tile_) * 64 + (size_t)(kk_) * 32; \
    gl_lds16(srcA + ko_, dstA + (((tile_) & 1) ? 8192 : 0) + ((kk_) ? 4096 : 0)); \
  } while (0)
#define STG_B(tile_, kk_) do { \
    const size_t ko_ = (size_t)(tile_) * 64 + (size_t)(kk_) * 32; \
    bf16_t* db_ = dstB + (((tile_) & 1) ? 24576 : 0) + ((kk_) ? 12288 : 0); \
    gl_lds16(srcB0 + ko_, db_); \
    gl_lds16(srcB1 + ko_, db_ + 4096); \
    gl_lds16(srcB2 + ko_, db_ + 8192); \
  } while (0)

  f32x16 acc[2][3] = {};

  STG_A(0, 0); STG_B(0, 0); STG_A(0, 1); STG_B(0, 1);
  STG_B(1, 0); STG_A(1, 0); STG_B(1, 1);
  asm volatile("s_waitcnt vmcnt(7)" ::: "memory");
  block_sync();

  for (int t = 0; t < nt; ++t) {
    const int s = t & 1;
    bf16x8 bfr[3][2];
    #pragma unroll
    for (int q = 0; q < 4; ++q) {
      const int kk = q >> 1, mh = q & 1;
      if (q == 0)      { if (t + 1 < nt) STG_A(t + 1, 1); }
      else if (q == 1) { if (t + 2 < nt) STG_B(t + 2, 0); }
      else if (q == 2) { if (t + 2 < nt) STG_A(t + 2, 0); }
      else             { if (t + 2 < nt) STG_B(t + 2, 1); }
      if (mh == 0) {
        const char* Bbase = (const char*)&Bs[s][kk][0];
        #pragma unroll
        for (int nb = 0; nb < 3; ++nb)
          #pragma unroll
          for (int u = 0; u < 2; ++u)
            bfr[nb][u] = *(const bf16x8*)(Bbase + olB[nb][u]);
      }
      const char* Abase = (const char*)&As[s][kk][0];
      bf16x8 af[2];
      #pragma unroll
      for (int u = 0; u < 2; ++u)
        af[u] = *(const bf16x8*)(Abase + olA[mh][u]);
      PHASE_MFMA_OPEN();
      #pragma unroll
      for (int u = 0; u < 2; ++u)
        #pragma unroll
        for (int nb = 0; nb < 3; ++nb)
          acc[mh][nb] =
            __builtin_amdgcn_mfma_f32_32x32x16_bf16(af[u], bfr[nb][u], acc[mh][nb], 0, 0, 0);
      PHASE_MFMA_CLOSE();
      if (q == 3) asm volatile("s_waitcnt vmcnt(7)" ::: "memory");
      block_sync();
    }
  }
#undef STG_A
#undef STG_B

  const float sval = (EPI == 5) ? sptr[0] : 0.0f;
  #pragma unroll
  for (int mb = 0; mb < 2; ++mb) {
    #pragma unroll
    for (int nb = 0; nb < 3; ++nb) {
      const int cg = tn + wn * 96 + nb * 32 + l31;
      #pragma unroll
      for (int rg = 0; rg < 16; ++rg) {
        const int r = tm + wm * 64 + mb * 32 + ROWMAP32(rg, kg);
        const float v = acc[mb][nb][rg];
        const size_t idx = (size_t)r * 768 + cg;
        if (EPI == 2) {
          ((bf16_t*)outp)[idx] = (bf16_t)v;
        } else if (EPI == 5) {
          ((float*)outp)[idx] = sval * ((const float*)auxp)[idx] + v;
        } else {
          ((float*)outp)[idx] = ((const float*)auxp)[idx] + v;
        }
      }
    }
  }
}

// ---------------------------------------------------------------------------
// LEAN fused FFN up-projections: 256 threads, 48 KB LDS -> 3 blocks/CU.
// Tile 128x128 (dual outputs), BK=32 double-buffered, 2 barriers/K-tile,
// counted vmcnt(6). Wave w owns rows w*32..w*32+31, all 128 cols.
// grid (24, 128).
// ---------------------------------------------------------------------------
__global__ __launch_bounds__(256) void gemm_ff13L(
    const bf16_t* __restrict__ A, const bf16_t* __restrict__ B1,
    const bf16_t* __restrict__ B3, bf16_t* __restrict__ G, int K)
{
  __shared__ bf16_t As[2][4096];    // [slot][128 rows x 32 elems]
  __shared__ bf16_t B1s[2][4096];
  __shared__ bf16_t B3s[2][4096];
  const int tid  = threadIdx.x;
  const int lane = tid & 63;
  const int wid  = tid >> 6;        // 0..3
  const int l31 = lane & 31, kg = lane >> 5;
  const int tm = blockIdx.y * 128;
  const int tn = blockIdx.x * 128;
  const int nt = K >> 5;            // K-tiles of 32

  // staging geometry: region 8KB = 2 chunks x (4 waves x 1024B)
  // chunk i, wave w: linear dest byte d = i*4096 + w*1024 + lane*16
  const bf16_t *srcA[2], *srcB1p[2], *srcB3p[2];
  #pragma unroll
  for (int i = 0; i < 2; ++i) {
    const int d = i * 4096 + wid * 1024 + lane * 16;
    const int p = SWZ(d);
    const int r = p >> 6, c = (p & 63) >> 1;
    srcA[i]   = A  + (size_t)(tm + r) * K + c;
    srcB1p[i] = B1 + (size_t)(tn + r) * K + c;
    srcB3p[i] = B3 + (size_t)(tn + r) * K + c;
  }
  bf16_t* dA  = &As[0][0]  + wid * 512;   // + slot*4096 + i*2048 (elems)
  bf16_t* dB1 = &B1s[0][0] + wid * 512;
  bf16_t* dB3 = &B3s[0][0] + wid * 512;

  // frag read offsets (swizzled, loop-invariant)
  int olA[2], olB[4][2];
  #pragma unroll
  for (int u = 0; u < 2; ++u) {
    const int o = ((wid * 32 + l31) << 6) + u * 32 + (kg << 4);
    olA[u] = SWZ(o);
  }
  #pragma unroll
  for (int nb = 0; nb < 4; ++nb)
    #pragma unroll
    for (int u = 0; u < 2; ++u) {
      const int o = ((nb * 32 + l31) << 6) + u * 32 + (kg << 4);
      olB[nb][u] = SWZ(o);
    }

  // STG(t): 6 loads (A 2, B1 2, B3 2) into slot t&1
#define STG(tile_) do { \
    const size_t ko_ = (size_t)(tile_) * 32; \
    const int so_ = ((tile_) & 1) ? 4096 : 0; \
    gl_lds16(srcA[0]   + ko_, dA  + so_); \
    gl_lds16(srcA[1]   + ko_, dA  + so_ + 2048); \
    gl_lds16(srcB1p[0] + ko_, dB1 + so_); \
    gl_lds16(srcB1p[1] + ko_, dB1 + so_ + 2048); \
    gl_lds16(srcB3p[0] + ko_, dB3 + so_); \
    gl_lds16(srcB3p[1] + ko_, dB3 + so_ + 2048); \
  } while (0)

  f32x16 acc1[4] = {};
  f32x16 acc3[4] = {};

  STG(0); STG(1);
  asm volatile("s_waitcnt vmcnt(6)" ::: "memory");
  block_sync();

  for (int t = 0; t < nt; ++t) {
    const int s = t & 1;
    const char* Abase  = (const char*)&As[s][0];
    const char* B1base = (const char*)&B1s[s][0];
    const char* B3base = (const char*)&B3s[s][0];
    bf16x8 af[2], b1r[4][2], b3r[4][2];
    #pragma unroll
    for (int u = 0; u < 2; ++u)
      af[u] = *(const bf16x8*)(Abase + olA[u]);
    #pragma unroll
    for (int nb = 0; nb < 4; ++nb)
      #pragma unroll
      for (int u = 0; u < 2; ++u) {
        b1r[nb][u] = *(const bf16x8*)(B1base + olB[nb][u]);
        b3r[nb][u] = *(const bf16x8*)(B3base + olB[nb][u]);
      }
    asm volatile("s_waitcnt lgkmcnt(0)" ::: "memory");
    __builtin_amdgcn_sched_barrier(0);
    block_sync();                       // all waves done reading slot s
    if (t + 2 < nt) STG(t + 2);         // slot s now free
    __builtin_amdgcn_s_setprio(1);
    #pragma unroll
    for (int u = 0; u < 2; ++u)
      #pragma unroll
      for (int nb = 0; nb < 4; ++nb) {
        acc1[nb] = __builtin_amdgcn_mfma_f32_32x32x16_bf16(af[u], b1r[nb][u], acc1[nb], 0, 0, 0);
        acc3[nb] = __builtin_amdgcn_mfma_f32_32x32x16_bf16(af[u], b3r[nb][u], acc3[nb], 0, 0, 0);
      }
    __builtin_amdgcn_s_setprio(0);
    __builtin_amdgcn_sched_barrier(0);
    if (t + 2 < nt) asm volatile("s_waitcnt vmcnt(6)" ::: "memory");
    else            asm volatile("s_waitcnt vmcnt(0)" ::: "memory");
    block_sync();
  }
#undef STG

  #pragma unroll
  for (int nb = 0; nb < 4; ++nb) {
    const int cg = tn + nb * 32 + l31;
    #pragma unroll
    for (int rg = 0; rg < 16; ++rg) {
      const int r2 = tm + wid * 32 + ROWMAP32(rg, kg);
      const float f1 = acc1[nb][rg];
      const float f3 = acc3[nb][rg];
      const float sg = f1 / (1.0f + __expf(-f1));
      G[(size_t)r2 * 3072 + cg] = (bf16_t)(sg * f3);
    }
  }
}

// ---------------------------------------------------------------------------
// Dual k/v projection: shared A staging, two B operands. 128x128, BK=64.
// ---------------------------------------------------------------------------
__global__ __launch_bounds__(256) void gemm_kv(
    const bf16_t* __restrict__ A, const bf16_t* __restrict__ Bk,
    const bf16_t* __restrict__ Bv, bf16_t* __restrict__ kout,
    bf16_t* __restrict__ vout, const float* __restrict__ bias,
    int M, int N, int K)
{
  __shared__ bf16_t Asl[128 * 64];
  __shared__ bf16_t Bks[128 * 64];
  __shared__ bf16_t Bvs[128 * 64];
  const int tid  = threadIdx.x;
  const int lane = tid & 63;
  const int wid  = tid >> 6;
  const int tm = blockIdx.y * 128;
  const int tn = blockIdx.x * 128;
  const int row0 = (wid & 1) * 64;
  const int col0 = (wid >> 1) * 64;
  const int fr = lane & 15;
  const int fg = lane >> 4;

  f32x4 acck[4][4] = {};
  f32x4 accv[4][4] = {};

  for (int k0 = 0; k0 < K; k0 += 64) {
    #pragma unroll
    for (int i = 0; i < 4; ++i) {
      const int ebase = (i * 4 + wid) * 512;
      const int e0 = ebase + lane * 8;
      const int r  = e0 >> 6;
      const int c  = e0 & 63;
      gl_lds16(A  + (size_t)(tm + r) * K + (k0 + c), &Asl[ebase]);
      gl_lds16(Bk + (size_t)(tn + r) * K + (k0 + c), &Bks[ebase]);
      gl_lds16(Bv + (size_t)(tn + r) * K + (k0 + c), &Bvs[ebase]);
    }
    __syncthreads();

    #pragma unroll
    for (int kk = 0; kk < 2; ++kk) {
      bf16x8 af[4], bk[4], bv2[4];
      #pragma unroll
      for (int m = 0; m < 4; ++m)
        af[m] = *(const bf16x8*)&Asl[(row0 + m * 16 + fr) * 64 + kk * 32 + fg * 8];
      #pragma unroll
      for (int n = 0; n < 4; ++n) {
        bk[n]  = *(const bf16x8*)&Bks[(col0 + n * 16 + fr) * 64 + kk * 32 + fg * 8];
        bv2[n] = *(const bf16x8*)&Bvs[(col0 + n * 16 + fr) * 64 + kk * 32 + fg * 8];
      }
      #pragma unroll
      for (int m = 0; m < 4; ++m) {
        #pragma unroll
        for (int n = 0; n < 4; ++n) {
          acck[m][n] = __builtin_amdgcn_mfma_f32_16x16x32_bf16(af[m], bk[n],  acck[m][n], 0, 0, 0);
          accv[m][n] = __builtin_amdgcn_mfma_f32_16x16x32_bf16(af[m], bv2[n], accv[m][n], 0, 0, 0);
        }
      }
    }
    __syncthreads();
  }

  #pragma unroll
  for (int m = 0; m < 4; ++m) {
    const int rb = row0 + m * 16 + fg * 4;
    #pragma unroll
    for (int n = 0; n < 4; ++n) {
      const int cg = tn + col0 + n * 16 + fr;
      #pragma unroll
      for (int j = 0; j < 4; ++j) {
        const int r = tm + rb + j;
        kout[(size_t)r * N + cg] = (bf16_t)acck[m][n][j];
        vout[(size_t)r * N + cg] = (bf16_t)(accv[m][n][j] + bias[cg]);
      }
    }
  }
}

// ---------------------------------------------------------------------------
// 128x128 BK=64 GEMM (16x16x32) for small shapes. EPI 7 = bf16 transposed.
// ---------------------------------------------------------------------------
template <int EPI>
__global__ __launch_bounds__(256) void gemm_bt(
    const bf16_t* __restrict__ A, const bf16_t* __restrict__ B,
    void* outp, const void* auxp, int M, int N, int K)
{
  __shared__ bf16_t Asl[128 * 64];
  __shared__ bf16_t Bsl[128 * 64];
  const int tid  = threadIdx.x;
  const int lane = tid & 63;
  const int wid  = tid >> 6;
  const int tm = blockIdx.y * 128;
  const int tn = blockIdx.x * 128;
  const int row0 = (wid & 1) * 64;
  const int col0 = (wid >> 1) * 64;
  const int fr = lane & 15;
  const int fg = lane >> 4;

  f32x4 acc[4][4] = {};

  for (int k0 = 0; k0 < K; k0 += 64) {
    #pragma unroll
    for (int i = 0; i < 4; ++i) {
      const int ebase = (i * 4 + wid) * 512;
      const int e0 = ebase + lane * 8;
      const int r  = e0 >> 6;
      const int c  = e0 & 63;
      gl_lds16(A + (size_t)(tm + r) * K + (k0 + c), &Asl[ebase]);
      gl_lds16(B + (size_t)(tn + r) * K + (k0 + c), &Bsl[ebase]);
    }
    __syncthreads();

    #pragma unroll
    for (int kk = 0; kk < 2; ++kk) {
      bf16x8 af[4], bfv[4];
      #pragma unroll
      for (int m = 0; m < 4; ++m)
        af[m] = *(const bf16x8*)&Asl[(row0 + m * 16 + fr) * 64 + kk * 32 + fg * 8];
      #pragma unroll
      for (int n = 0; n < 4; ++n)
        bfv[n] = *(const bf16x8*)&Bsl[(col0 + n * 16 + fr) * 64 + kk * 32 + fg * 8];
      #pragma unroll
      for (int m = 0; m < 4; ++m) {
        #pragma unroll
        for (int n = 0; n < 4; ++n)
          acc[m][n] = __builtin_amdgcn_mfma_f32_16x16x32_bf16(af[m], bfv[n], acc[m][n], 0, 0, 0);
      }
    }
    __syncthreads();
  }

  #pragma unroll
  for (int m = 0; m < 4; ++m) {
    const int rb = row0 + m * 16 + fg * 4;
    #pragma unroll
    for (int n = 0; n < 4; ++n) {
      const int cg = tn + col0 + n * 16 + fr;
      #pragma unroll
      for (int j = 0; j < 4; ++j) {
        const int r = tm + rb + j;
        const float v = acc[m][n][j];
        if (EPI == 7) {
          ((bf16_t*)outp)[(size_t)cg * M + r] = (bf16_t)v;
        } else {
          ((bf16_t*)outp)[(size_t)r * N + cg] = (bf16_t)v;
        }
      }
    }
  }
}

// ---------------------------------------------------------------------------
__global__ __launch_bounds__(256) void rms_all(
    const float* __restrict__ cb, const float* __restrict__ lt,
    const float* __restrict__ ncs, const float* __restrict__ nqs,
    bf16_t* __restrict__ nc, bf16_t* __restrict__ nq)
{
  const int row = blockIdx.x, t = threadIdx.x;
  const float* xr;
  const float* scale;
  bf16_t* orow;
  if (row < 2048) {
    xr = cb + (size_t)row * 768; scale = ncs; orow = nc + (size_t)row * 768;
  } else {
    const int r2 = row - 2048;
    xr = lt + (size_t)r2 * 768; scale = nqs; orow = nq + (size_t)r2 * 768;
  }
  const float v0 = xr[t], v1 = xr[t + 256], v2 = xr[t + 512];
  float ss = v0 * v0 + v1 * v1 + v2 * v2;
  #pragma unroll
  for (int m = 32; m; m >>= 1) ss += __shfl_xor(ss, m);
  __shared__ float red[4];
  if ((t & 63) == 0) red[t >> 6] = ss;
  __syncthreads();
  const float tot = red[0] + red[1] + red[2] + red[3];
  const float inv = rsqrtf(tot / 768.0f + 1e-6f);
  orow[t]       = (bf16_t)(v0 * inv * scale[t]);
  orow[t + 256] = (bf16_t)(v1 * inv * scale[t + 256]);
  orow[t + 512] = (bf16_t)(v2 * inv * scale[t + 512]);
}

// ---------------------------------------------------------------------------
__global__ __launch_bounds__(256) void rms_rows(const float* __restrict__ x,
                                                const float* __restrict__ scale,
                                                bf16_t* __restrict__ out)
{
  const int row = blockIdx.x, t = threadIdx.x;
  const float* xr = x + (size_t)row * 768;
  const float v0 = xr[t], v1 = xr[t + 256], v2 = xr[t + 512];
  float ss = v0 * v0 + v1 * v1 + v2 * v2;
  #pragma unroll
  for (int m = 32; m; m >>= 1) ss += __shfl_xor(ss, m);
  __shared__ float red[4];
  if ((t & 63) == 0) red[t >> 6] = ss;
  __syncthreads();
  const float tot = red[0] + red[1] + red[2] + red[3];
  const float inv = rsqrtf(tot / 768.0f + 1e-6f);
  bf16_t* orow = out + (size_t)row * 768;
  orow[t]       = (bf16_t)(v0 * inv * scale[t]);
  orow[t + 256] = (bf16_t)(v1 * inv * scale[t + 256]);
  orow[t + 512] = (bf16_t)(v2 * inv * scale[t + 512]);
}

// ---------------------------------------------------------------------------
__global__ __launch_bounds__(128) void trig_fill(float* __restrict__ trig)
{
  const int p = blockIdx.x, t = threadIdx.x;
  #pragma unroll
  for (int j = 0; j < 3; ++j) {
    const int i = t + j * 128;
    const float invf = expf(-(float)i * (9.210340371976184f / 384.0f));
    const float ang  = (float)p * invf;
    trig[(size_t)p * 768 + i]       = cosf(ang);
    trig[(size_t)p * 768 + 384 + i] = sinf(ang);
  }
}

// ---------------------------------------------------------------------------
__global__ __launch_bounds__(128) void rope_qk(const bf16_t* __restrict__ qsrc,
                                               const bf16_t* __restrict__ ksrc,
                                               const int* __restrict__ pos,
                                               const float* __restrict__ trig,
                                               bf16_t* __restrict__ qdst,
                                               bf16_t* __restrict__ kdst)
{
  const int bid = blockIdx.x, t = threadIdx.x;
  const bf16_t* s;
  bf16_t* d;
  int p;
  if (bid < NROWS) {
    p = pos[bid];
    s = qsrc + (size_t)bid * 768;
    d = qdst + (size_t)bid * 768;
  } else {
    const int row = bid - NROWS;
    p = pos[row];
    s = ksrc + (size_t)(row & 2047) * 768;
    d = kdst + (size_t)row * 768;
  }
  const float* tr = trig + (size_t)p * 768;
  #pragma unroll
  for (int j = 0; j < 3; ++j) {
    const int i = t + j * 128;
    const float x1 = (float)s[i], x2 = (float)s[i + 384];
    const float c = tr[i], sn = tr[i + 384];
    d[i]       = (bf16_t)(x1 * c - x2 * sn);
    d[i + 384] = (bf16_t)(x1 * sn + x2 * c);
  }
}

// ---------------------------------------------------------------------------
__global__ __launch_bounds__(256) void softmax_g(const float* __restrict__ la,
                                                 float* __restrict__ lat,
                                                 float* __restrict__ z,
                                                 bf16_t* __restrict__ zb,
                                                 const float* __restrict__ taup,
                                                 const float* __restrict__ gnsp)
{
  const int row = blockIdx.x, t = threadIdx.x;
  const float tau = taup[0], gns = gnsp[0];
  const float* lar = la + (size_t)row * 2048;
  float* latr = lat + (size_t)row * 2048;
  float* zr   = z   + (size_t)row * 2048;
  bf16_t* zbr = zb  + (size_t)row * 2048;
  const uint32_t base = (uint32_t)row * 2048u;

  float vals[8];
  float mx = -3.0e38f;
  #pragma unroll
  for (int j = 0; j < 8; ++j) {
    const int c = t + j * 256;
    const uint32_t flat = base + (uint32_t)c;
    const uint2 rr = threefry2x32(0u, 42u, 0u, flat);
    const uint32_t bits = rr.x ^ rr.y;
    const float u = __uint_as_float((bits >> 9) | 0x3f800000u) - 1.0f;
    const float gum = -__logf(-__logf(u + 1e-10f) + 1e-10f);
    const float v = (lar[c] + gns * gum) / tau;
    vals[j] = v;
    latr[c] = v;
    mx = fmaxf(mx, v);
  }
  #pragma unroll
  for (int m = 32; m; m >>= 1) mx = fmaxf(mx, __shfl_xor(mx, m));
  __shared__ float redm[4];
  if ((t & 63) == 0) redm[t >> 6] = mx;
  __syncthreads();
  mx = fmaxf(fmaxf(redm[0], redm[1]), fmaxf(redm[2], redm[3]));

  float sum = 0.0f;
  #pragma unroll
  for (int j = 0; j < 8; ++j) { vals[j] = __expf(vals[j] - mx); sum += vals[j]; }
  #pragma unroll
  for (int m = 32; m; m >>= 1) sum += __shfl_xor(sum, m);
  __shared__ float reds[4];
  if ((t & 63) == 0) reds[t >> 6] = sum;
  __syncthreads();
  sum = reds[0] + reds[1] + reds[2] + reds[3];

  const float rinv = 1.0f / sum;
  #pragma unroll
  for (int j = 0; j < 8; ++j) {
    const int c = t + j * 256;
    const float zz = vals[j] * rinv;
    zr[c]  = zz;
    zbr[c] = (bf16_t)zz;
  }
}

// ---------------------------------------------------------------------------
__global__ __launch_bounds__(256) void convert_w(
    const float* __restrict__ wq, const float* __restrict__ wk,
    const float* __restrict__ wv, const float* __restrict__ wc,
    const float* __restrict__ w1, const float* __restrict__ w3,
    const float* __restrict__ w2, bf16_t* __restrict__ dst)
{
  const int idx = blockIdx.x * 256 + threadIdx.x;
  const float* src; int off;
  if      (idx < 589824)  { src = wq; off = 0; }
  else if (idx < 1179648) { src = wk; off = 589824; }
  else if (idx < 1769472) { src = wv; off = 1179648; }
  else if (idx < 2359296) { src = wc; off = 1769472; }
  else if (idx < 4718592) { src = w1; off = 2359296; }
  else if (idx < 7077888) { src = w3; off = 4718592; }
  else                    { src = w2; off = 7077888; }
  dst[idx] = (bf16_t)src[idx - off];
}

// ---------------------------------------------------------------------------
extern "C" void kernel_launch(void* const* d_in, const int* in_sizes, int n_in,
                              void* d_out, int out_size, void* d_ws, size_t ws_size,
                              hipStream_t stream)
{
  (void)in_sizes; (void)n_in; (void)out_size; (void)ws_size;
  const float* latents   = (const float*)d_in[0];
  const float* taup      = (const float*)d_in[1];
  const float* rsp       = (const float*)d_in[2];
  const float* gnsp      = (const float*)d_in[3];
  const int*   positions = (const int*)d_in[4];
  const float* codebook  = (const float*)d_in[5];
  const float* ncs       = (const float*)d_in[6];
  const float* nqs       = (const float*)d_in[7];
  const float* nfs       = (const float*)d_in[8];
  const float* Wq = (const float*)d_in[9];
  const float* Wk = (const float*)d_in[10];
  const float* Wv = (const float*)d_in[11];
  const float* bv = (const float*)d_in[12];
  const float* Wc = (const float*)d_in[13];
  const float* W1 = (const float*)d_in[14];
  const float* W2 = (const float*)d_in[15];
  const float* W3 = (const float*)d_in[16];

  char* ws = (char*)d_ws;
  char* ob = (char*)d_out;

  bf16_t* wbf  = (bf16_t*)(ws + WS_W);
  float*  trig = (float*)(ws + WS_TRIG);
  bf16_t* vcT  = (bf16_t*)(ws + WS_VCT);
  bf16_t* nc   = (bf16_t*)(ws + WS_NC);
  bf16_t* nq   = (bf16_t*)(ws + WS_NQ);
  bf16_t* zbuf = (bf16_t*)(ws + WS_Z);
  bf16_t* hbuf = (bf16_t*)(ws + WS_H);
  bf16_t* gbuf = (bf16_t*)(ws + WS_G);
  bf16_t* vbuf = (bf16_t*)(ws + WS_VB);

  float*  out_cb  = (float*)(ob + DO_CB);
  float*  out_la  = (float*)(ob + DO_LA);
  float*  out_lat = (float*)(ob + DO_LAT);
  float*  out_z   = (float*)(ob + DO_Z);
  bf16_t* qbase   = (bf16_t*)(ob + DO_QBASE);
  bf16_t* kbase   = (bf16_t*)(ob + DO_KBASE);
  bf16_t* qrope   = (bf16_t*)(ob + DO_QROPE);
  bf16_t* krope   = (bf16_t*)(ob + DO_KROPE);

  // P0: weight cast, merged norms, trig table
  convert_w<<<dim3(WTOT / 256), dim3(256), 0, stream>>>(Wq, Wk, Wv, Wc, W1, W3, W2, wbf);
  rms_all<<<dim3(C_ + NROWS), dim3(256), 0, stream>>>(codebook, latents, ncs, nqs, nc, nq);
  trig_fill<<<dim3(2048), dim3(128), 0, stream>>>(trig);

  // P1: projections. k,v in one dual-B kernel; vcT = (v@Wc^T)^T
  gemm_kv<<<dim3(6, 16), dim3(256), 0, stream>>>(nc, wbf + WK_OFF, wbf + WV_OFF,
                                                 kbase, vbuf, bv, C_, D_, D_);
  gemm_bt<7><<<dim3(6, 16), dim3(256), 0, stream>>>(vbuf, wbf + WC_OFF, vcT, nullptr, C_, D_, D_);
  gemm_n384<2><<<dim3(2, 128), dim3(512), 0, stream>>>(nq, wbf + WQ_OFF, qbase, nullptr, nullptr, D_);

  // P2: RoPE (q and k in one dispatch)
  rope_qk<<<dim3(2 * NROWS), dim3(128), 0, stream>>>(qbase, kbase, positions, trig, qrope, krope);

  // P3: log_alpha = q k^T / sqrt(D), batched over 8
  gemm8p<1><<<dim3(8, 8, 8), dim3(512), 0, stream>>>(qrope, krope, out_la, nullptr, nullptr,
                                                     N_, C_, D_, (long)N_ * D_, (long)C_ * D_, (long)N_ * C_);

  // P4: gumbel + log_alpha_tau + softmax z
  softmax_g<<<dim3(NROWS), dim3(256), 0, stream>>>(out_la, out_lat, out_z, zbuf, taup, gnsp);

  // P5: attn_output = rs*latents + z @ vc   (fused z@v@Wc^T, K=2048)
  gemm_n384<5><<<dim3(2, 128), dim3(512), 0, stream>>>(zbuf, vcT, out_cb, latents, rsp, C_);

  // P7: h = rms_norm(attn_output)
  rms_rows<<<dim3(NROWS), dim3(256), 0, stream>>>(out_cb, nfs, hbuf);

  // P8: FFN — lean high-occupancy fused up-projections, then down-projection
  gemm_ff13L<<<dim3(24, 128), dim3(256), 0, stream>>>(hbuf, wbf + W1_OFF, wbf + W3_OFF, gbuf, D_);
  gemm_n384<6><<<dim3(2, 128), dim3(512), 0, stream>>>(gbuf, wbf + W2_OFF, out_cb, out_cb, nullptr, H_);
}

// Round 13
// 792.973 us; speedup vs baseline: 1.1485x; 1.1485x over previous
//
#include <hip/hip_runtime.h>
#include <cstdint>
#include <cstddef>

// ---------------------------------------------------------------------------
// AttnCodebook on MI355X (gfx950). Round 13: revert pipelined GEMM cores to
// 16x16x32 fragments (32x32 fragment reads are provably 4-way bank-conflicted
// at 64B row stride: 32 rows -> 8 16B-slots, 2-bit swizzle can't fix; counters
// showed 14-21M conflicts in every 32x32 variant). Keeps XCD swizzles (r8),
// rms_all/gemm_kv merges (r9), vc fusion, fast-math, merged rope.
// ---------------------------------------------------------------------------

typedef __bf16 bf16_t;
typedef __bf16 bf16x8 __attribute__((ext_vector_type(8)));
typedef float  f32x4  __attribute__((ext_vector_type(4)));

#define B_    8
#define N_    2048
#define D_    768
#define C_    2048
#define H_    3072
#define NROWS 16384   // B_*N_

// weight bf16 arena (element offsets)
#define WQ_OFF 0
#define WK_OFF 589824
#define WV_OFF 1179648
#define WC_OFF 1769472
#define W1_OFF 2359296
#define W3_OFF 4718592
#define W2_OFF 7077888
#define WTOT   9437184

// ---- d_ws layout (bytes). ws_size ~1.8 GB.
#define WS_W     0ull
#define WS_TRIG  18874368ull
#define WS_VCT   25165824ull   // bf16 vcT [768][2048]
#define WS_NC    28311552ull   // bf16 normed_context [2048][768]
#define WS_NQ    31457280ull   // bf16 normed_queries
#define WS_Z     56623104ull   // bf16 z [16384][2048]
#define WS_H     28311552ull   // bf16 h (reuse NC/NQ region, live P7-P8)
#define WS_G     157286400ull  // bf16 g [16384][3072]
#define WS_VB    257949696ull  // bf16 v [2048][768]

// ---- d_out layout: [cb][la][lat][z]
#define DO_CB    0ull
#define DO_LA    50331648ull
#define DO_LAT   184549376ull
#define DO_Z     318767104ull
// scratch parked in LAT section (dead before lat written); bf16 bases
#define DO_QBASE 184549376ull
#define DO_KBASE (184549376ull + 50331648ull)
#define DO_QROPE (234881024ull + 6291456ull)
#define DO_KROPE (241172480ull + 25165824ull)

// ---------------------------------------------------------------------------
__device__ __forceinline__ void gl_lds16(const void* g, void* l) {
  __builtin_amdgcn_global_load_lds((__attribute__((address_space(1))) void*)(g),
                                   (__attribute__((address_space(3))) void*)(l),
                                   16, 0, 0);
}

__device__ __forceinline__ void block_sync() {
  __builtin_amdgcn_sched_barrier(0);
  asm volatile("" ::: "memory");
  __builtin_amdgcn_s_barrier();
  asm volatile("" ::: "memory");
  __builtin_amdgcn_sched_barrier(0);
}

__device__ __forceinline__ uint32_t rotl32(uint32_t v, int d) {
  return (v << d) | (v >> (32 - d));
}
__device__ __forceinline__ void tf_round(uint32_t& x0, uint32_t& x1, int r) {
  x0 += x1; x1 = rotl32(x1, r); x1 ^= x0;
}
__device__ __forceinline__ uint2 threefry2x32(uint32_t k0, uint32_t k1,
                                              uint32_t x0, uint32_t x1) {
  const uint32_t k2 = k0 ^ k1 ^ 0x1BD11BDAu;
  x0 += k0; x1 += k1;
  tf_round(x0,x1,13); tf_round(x0,x1,15); tf_round(x0,x1,26); tf_round(x0,x1,6);
  x0 += k1; x1 += k2 + 1u;
  tf_round(x0,x1,17); tf_round(x0,x1,29); tf_round(x0,x1,16); tf_round(x0,x1,24);
  x0 += k2; x1 += k0 + 2u;
  tf_round(x0,x1,13); tf_round(x0,x1,15); tf_round(x0,x1,26); tf_round(x0,x1,6);
  x0 += k0; x1 += k1 + 3u;
  tf_round(x0,x1,17); tf_round(x0,x1,29); tf_round(x0,x1,16); tf_round(x0,x1,24);
  x0 += k1; x1 += k2 + 4u;
  tf_round(x0,x1,13); tf_round(x0,x1,15); tf_round(x0,x1,26); tf_round(x0,x1,6);
  x0 += k2; x1 += k0 + 5u;
  return make_uint2(x0, x1);
}

#define SWZ(o) ((o) ^ ((((o) >> 7) & 3) << 4))

#define PHASE_MFMA_OPEN() do { \
    block_sync(); \
    asm volatile("s_waitcnt lgkmcnt(0)" ::: "memory"); \
    __builtin_amdgcn_sched_barrier(0); \
    __builtin_amdgcn_s_setprio(1); \
  } while (0)
#define PHASE_MFMA_CLOSE() do { \
    __builtin_amdgcn_s_setprio(0); \
    __builtin_amdgcn_sched_barrier(0); \
  } while (0)

// ---------------------------------------------------------------------------
// 256x256 8-wave 4-phase GEMM, 16x16x32 MFMA. C[M,N]=A[M,K]@B[N,K]^T. (qk)
// ---------------------------------------------------------------------------
template <int EPI>
__global__ __launch_bounds__(512, 2) void gemm8p(
    const bf16_t* __restrict__ A, const bf16_t* __restrict__ B,
    void* outp, const void* auxp, const float* sptr,
    int M, int N, int K, long sA, long sB, long sO)
{
  __shared__ bf16_t As[2][2][8192];
  __shared__ bf16_t Bs[2][2][8192];
  const int tid  = threadIdx.x;
  const int lane = tid & 63;
  const int wid  = tid >> 6;
  const int wm = wid >> 2, wn = wid & 3;
  const int fr = lane & 15, fg = lane >> 4;

  // XCD swizzle (bijective over 512): lin%8 -> chunk of 64 = one bz
  const int lin = (blockIdx.z * gridDim.y + blockIdx.y) * gridDim.x + blockIdx.x;
  const int swzb = (lin & 7) * 64 + (lin >> 3);
  const int bz = swzb >> 6;
  const int ny = (swzb & 63) >> 3;
  const int nx = swzb & 7;

  const bf16_t* Ab = A + (size_t)bz * (size_t)sA;
  const bf16_t* Bb = B + (size_t)bz * (size_t)sB;
  const int tm = ny * 256;
  const int tn = nx * 256;
  const int nt = K >> 6;

  const bf16_t *srcA0, *srcA1, *srcB0, *srcB1;
  {
    const int d0 = wid * 1024 + lane * 16;
    const int p0 = SWZ(d0);
    srcA0 = Ab + (size_t)(tm + (p0 >> 6)) * K + ((p0 & 63) >> 1);
    srcB0 = Bb + (size_t)(tn + (p0 >> 6)) * K + ((p0 & 63) >> 1);
    const int d1 = 8192 + wid * 1024 + lane * 16;
    const int p1 = SWZ(d1);
    srcA1 = Ab + (size_t)(tm + (p1 >> 6)) * K + ((p1 & 63) >> 1);
    srcB1 = Bb + (size_t)(tn + (p1 >> 6)) * K + ((p1 & 63) >> 1);
  }
  bf16_t* dstA = &As[0][0][0] + wid * 512;
  bf16_t* dstB = &Bs[0][0][0] + wid * 512;

  // hoisted swizzled read offsets (16x16 fragments: fr rows, fg col-slot)
  int olB[4], olA[2][4];
  #pragma unroll
  for (int n = 0; n < 4; ++n) {
    const int o = ((wn * 64 + n * 16 + fr) << 6) + (fg << 4);
    olB[n] = SWZ(o);
  }
  #pragma unroll
  for (int mh = 0; mh < 2; ++mh)
    #pragma unroll
    for (int j = 0; j < 4; ++j) {
      const int o = ((wm * 128 + mh * 64 + j * 16 + fr) << 6) + (fg << 4);
      olA[mh][j] = SWZ(o);
    }

#define STG_A(tile_, kk_) do { \
    const size_t ko_ = (size_t)(tile_) * 64 + (size_t)(kk_) * 32; \
    bf16_t* db_ = dstA + (((tile_) & 1) ? 16384 : 0) + ((kk_) ? 8192 : 0); \
    gl_lds16(srcA0 + ko_, db_); \
    gl_lds16(srcA1 + ko_, db_ + 4096); \
  } while (0)
#define STG_B(tile_, kk_) do { \
    const size_t ko_ = (size_t)(tile_) * 64 + (size_t)(kk_) * 32; \
    bf16_t* db_ = dstB + (((tile_) & 1) ? 16384 : 0) + ((kk_) ? 8192 : 0); \
    gl_lds16(srcB0 + ko_, db_); \
    gl_lds16(srcB1 + ko_, db_ + 4096); \
  } while (0)

  f32x4 acc[8][4] = {};

  STG_A(0, 0); STG_B(0, 0); STG_A(0, 1); STG_B(0, 1);
  STG_B(1, 0); STG_A(1, 0); STG_B(1, 1);
  asm volatile("s_waitcnt vmcnt(6)" ::: "memory");
  block_sync();

  for (int t = 0; t < nt; ++t) {
    const int s = t & 1;
    bf16x8 bfr[4];
    #pragma unroll
    for (int q = 0; q < 4; ++q) {
      const int kk = q >> 1, mh = q & 1;
      if (q == 0)      { if (t + 1 < nt) STG_A(t + 1, 1); }
      else if (q == 1) { if (t + 2 < nt) STG_B(t + 2, 0); }
      else if (q == 2) { if (t + 2 < nt) STG_A(t + 2, 0); }
      else             { if (t + 2 < nt) STG_B(t + 2, 1); }
      if (mh == 0) {
        const char* Bbase = (const char*)&Bs[s][kk][0];
        #pragma unroll
        for (int n = 0; n < 4; ++n)
          bfr[n] = *(const bf16x8*)(Bbase + olB[n]);
      }
      const char* Abase = (const char*)&As[s][kk][0];
      bf16x8 af[4];
      #pragma unroll
      for (int j = 0; j < 4; ++j)
        af[j] = *(const bf16x8*)(Abase + olA[mh][j]);
      PHASE_MFMA_OPEN();
      #pragma unroll
      for (int j = 0; j < 4; ++j) {
        #pragma unroll
        for (int n = 0; n < 4; ++n)
          acc[mh * 4 + j][n] =
            __builtin_amdgcn_mfma_f32_16x16x32_bf16(af[j], bfr[n], acc[mh * 4 + j][n], 0, 0, 0);
      }
      PHASE_MFMA_CLOSE();
      if (q == 3) asm volatile("s_waitcnt vmcnt(6)" ::: "memory");
      block_sync();
    }
  }
#undef STG_A
#undef STG_B

  #pragma unroll
  for (int m = 0; m < 8; ++m) {
    const int rb = wm * 128 + m * 16 + fg * 4;
    #pragma unroll
    for (int n = 0; n < 4; ++n) {
      const int cg = tn + wn * 64 + n * 16 + fr;
      #pragma unroll
      for (int j = 0; j < 4; ++j) {
        const int r = tm + rb + j;
        const float v = acc[m][n][j];
        const size_t idx = (size_t)r * N + cg;
        if (EPI == 1) {
          ((float*)outp)[(size_t)bz * sO + idx] = v * 0.03608439182435161f; // 1/sqrt(768)
        } else {
          ((float*)outp)[(size_t)bz * sO + idx] = v;
        }
      }
    }
  }
}

// ---------------------------------------------------------------------------
// BM=128 x BN=384 8-wave 4-phase GEMM, 16x16x32 MFMA. grid (2, 128).
// EPI: 2=bf16  5=f32 s*aux+acc  6=f32 aux+acc
// ---------------------------------------------------------------------------
template <int EPI>
__global__ __launch_bounds__(512, 2) void gemm_n384(
    const bf16_t* __restrict__ A, const bf16_t* __restrict__ B,
    void* outp, const void* auxp, const float* sptr, int K)
{
  __shared__ bf16_t As[2][2][4096];
  __shared__ bf16_t Bs[2][2][12288];
  const int tid  = threadIdx.x;
  const int lane = tid & 63;
  const int wid  = tid >> 6;
  const int wm = wid >> 2, wn = wid & 3;
  const int fr = lane & 15, fg = lane >> 4;

  // XCD swizzle (bijective over 256)
  const int lin = blockIdx.y * 2 + blockIdx.x;
  const int swzb = (lin & 7) * 32 + (lin >> 3);
  const int ny = swzb >> 1;
  const int nx = swzb & 1;

  const int tm = ny * 128;
  const int tn = nx * 384;
  const int nt = K >> 6;

  const bf16_t *srcA, *srcB0, *srcB1, *srcB2;
  {
    const int d = wid * 1024 + lane * 16;
    const int p = SWZ(d);
    srcA = A + (size_t)(tm + (p >> 6)) * K + ((p & 63) >> 1);
    srcB0 = B + (size_t)(tn + (p >> 6)) * K + ((p & 63) >> 1);
    const int d1 = 8192 + d, p1 = SWZ(d1);
    srcB1 = B + (size_t)(tn + (p1 >> 6)) * K + ((p1 & 63) >> 1);
    const int d2 = 16384 + d, p2 = SWZ(d2);
    srcB2 = B + (size_t)(tn + (p2 >> 6)) * K + ((p2 & 63) >> 1);
  }
  bf16_t* dstA = &As[0][0][0] + wid * 512;
  bf16_t* dstB = &Bs[0][0][0] + wid * 512;

  int olB[6], olA[2][2];
  #pragma unroll
  for (int n = 0; n < 6; ++n) {
    const int o = ((wn * 96 + n * 16 + fr) << 6) + (fg << 4);
    olB[n] = SWZ(o);
  }
  #pragma unroll
  for (int mh = 0; mh < 2; ++mh)
    #pragma unroll
    for (int j = 0; j < 2; ++j) {
      const int o = ((wm * 64 + (mh * 2 + j) * 16 + fr) << 6) + (fg << 4);
      olA[mh][j] = SWZ(o);
    }

#define STG_A(tile_, kk_) do { \
    const size_t ko_ = (size_t)(tile_) * 64 + (size_t)(kk_) * 32; \
    gl_lds16(srcA + ko_, dstA + (((tile_) & 1) ? 8192 : 0) + ((kk_) ? 4096 : 0)); \
  } while (0)
#define STG_B(tile_, kk_) do { \
    const size_t ko_ = (size_t)(tile_) * 64 + (size_t)(kk_) * 32; \
    bf16_t* db_ = dstB + (((tile_) & 1) ? 24576 : 0) + ((kk_) ? 12288 : 0); \
    gl_lds16(srcB0 + ko_, db_); \
    gl_lds16(srcB1 + ko_, db_ + 4096); \
    gl_lds16(srcB2 + ko_, db_ + 8192); \
  } while (0)

  f32x4 acc[4][6] = {};

  STG_A(0, 0); STG_B(0, 0); STG_A(0, 1); STG_B(0, 1);
  STG_B(1, 0); STG_A(1, 0); STG_B(1, 1);
  asm volatile("s_waitcnt vmcnt(7)" ::: "memory");
  block_sync();

  for (int t = 0; t < nt; ++t) {
    const int s = t & 1;
    bf16x8 bfr[6];
    #pragma unroll
    for (int q = 0; q < 4; ++q) {
      const int kk = q >> 1, mh = q & 1;
      if (q == 0)      { if (t + 1 < nt) STG_A(t + 1, 1); }
      else if (q == 1) { if (t + 2 < nt) STG_B(t + 2, 0); }
      else if (q == 2) { if (t + 2 < nt) STG_A(t + 2, 0); }
      else             { if (t + 2 < nt) STG_B(t + 2, 1); }
      if (mh == 0) {
        const char* Bbase = (const char*)&Bs[s][kk][0];
        #pragma unroll
        for (int n = 0; n < 6; ++n)
          bfr[n] = *(const bf16x8*)(Bbase + olB[n]);
      }
      const char* Abase = (const char*)&As[s][kk][0];
      bf16x8 af[2];
      #pragma unroll
      for (int j = 0; j < 2; ++j)
        af[j] = *(const bf16x8*)(Abase + olA[mh][j]);
      PHASE_MFMA_OPEN();
      #pragma unroll
      for (int j = 0; j < 2; ++j) {
        #pragma unroll
        for (int n = 0; n < 6; ++n)
          acc[mh * 2 + j][n] =
            __builtin_amdgcn_mfma_f32_16x16x32_bf16(af[j], bfr[n], acc[mh * 2 + j][n], 0, 0, 0);
      }
      PHASE_MFMA_CLOSE();
      if (q == 3) asm volatile("s_waitcnt vmcnt(7)" ::: "memory");
      block_sync();
    }
  }
#undef STG_A
#undef STG_B

  const float sval = (EPI == 5) ? sptr[0] : 0.0f;
  #pragma unroll
  for (int m = 0; m < 4; ++m) {
    const int rb = wm * 64 + m * 16 + fg * 4;
    #pragma unroll
    for (int n = 0; n < 6; ++n) {
      const int cg = tn + wn * 96 + n * 16 + fr;
      #pragma unroll
      for (int j = 0; j < 4; ++j) {
        const int r = tm + rb + j;
        const float v = acc[m][n][j];
        const size_t idx = (size_t)r * 768 + cg;
        if (EPI == 2) {
          ((bf16_t*)outp)[idx] = (bf16_t)v;
        } else if (EPI == 5) {
          ((float*)outp)[idx] = sval * ((const float*)auxp)[idx] + v;
        } else {
          ((float*)outp)[idx] = ((const float*)auxp)[idx] + v;
        }
      }
    }
  }
}

// ---------------------------------------------------------------------------
// Fused FFN up-projections, 16x16x32: silu(h@W1^T)*(h@W3^T) -> G. grid (24,64)
// XCD stripe map from round 8 (841us config).
// ---------------------------------------------------------------------------
__global__ __launch_bounds__(512, 2) void gemm_ff13(
    const bf16_t* __restrict__ A, const bf16_t* __restrict__ B1,
    const bf16_t* __restrict__ B3, bf16_t* __restrict__ G, int K)
{
  __shared__ bf16_t As[2][2][8192];
  __shared__ bf16_t B1s[2][2][4096];
  __shared__ bf16_t B3s[2][2][4096];
  const int tid  = threadIdx.x;
  const int lane = tid & 63;
  const int wid  = tid >> 6;
  const int wm = wid >> 2, wn = wid & 3;
  const int fr = lane & 15, fg = lane >> 4;

  // XCD swizzle (bijective over 1536): chunk 192 per XCD, striped 3x x 8y
  const int lin = blockIdx.y * 24 + blockIdx.x;
  const int swzb = (lin & 7) * 192 + (lin >> 3);
  const int cj = swzb / 192;
  const int local = swzb - cj * 192;
  const int st = local / 24;
  const int rr = local - st * 24;
  const int nx = cj * 3 + (rr % 3);
  const int ny = st * 8 + (rr / 3);

  const int tm = ny * 256;
  const int tn = nx * 128;
  const int nt = K >> 6;

  const bf16_t *srcA0, *srcA1, *srcB1p, *srcB3p;
  {
    const int d0 = wid * 1024 + lane * 16;
    const int p0 = SWZ(d0);
    srcA0 = A + (size_t)(tm + (p0 >> 6)) * K + ((p0 & 63) >> 1);
    srcB1p = B1 + (size_t)(tn + (p0 >> 6)) * K + ((p0 & 63) >> 1);
    srcB3p = B3 + (size_t)(tn + (p0 >> 6)) * K + ((p0 & 63) >> 1);
    const int d1 = 8192 + d0, p1 = SWZ(d1);
    srcA1 = A + (size_t)(tm + (p1 >> 6)) * K + ((p1 & 63) >> 1);
  }
  bf16_t* dstA  = &As[0][0][0]  + wid * 512;
  bf16_t* dstB1 = &B1s[0][0][0] + wid * 512;
  bf16_t* dstB3 = &B3s[0][0][0] + wid * 512;

  int olB[2], olA[2][4];
  #pragma unroll
  for (int n = 0; n < 2; ++n) {
    const int o = ((wn * 32 + n * 16 + fr) << 6) + (fg << 4);
    olB[n] = SWZ(o);
  }
  #pragma unroll
  for (int mh = 0; mh < 2; ++mh)
    #pragma unroll
    for (int j = 0; j < 4; ++j) {
      const int o = ((wm * 128 + mh * 64 + j * 16 + fr) << 6) + (fg << 4);
      olA[mh][j] = SWZ(o);
    }

#define STG_A(tile_, kk_) do { \
    const size_t ko_ = (size_t)(tile_) * 64 + (size_t)(kk_) * 32; \
    bf16_t* db_ = dstA + (((tile_) & 1) ? 16384 : 0) + ((kk_) ? 8192 : 0); \
    gl_lds16(srcA0 + ko_, db_); \
    gl_lds16(srcA1 + ko_, db_ + 4096); \
  } while (0)
#define STG_B(tile_, kk_) do { \
    const size_t ko_ = (size_t)(tile_) * 64 + (size_t)(kk_) * 32; \
    const int ro_ = (((tile_) & 1) ? 8192 : 0) + ((kk_) ? 4096 : 0); \
    gl_lds16(srcB1p + ko_, dstB1 + ro_); \
    gl_lds16(srcB3p + ko_, dstB3 + ro_); \
  } while (0)

  f32x4 acc1[8][2] = {};
  f32x4 acc3[8][2] = {};

  STG_A(0, 0); STG_B(0, 0); STG_A(0, 1); STG_B(0, 1);
  STG_B(1, 0); STG_A(1, 0); STG_B(1, 1);
  asm volatile("s_waitcnt vmcnt(6)" ::: "memory");
  block_sync();

  for (int t = 0; t < nt; ++t) {
    const int s = t & 1;
    bf16x8 b1r[2], b3r[2];
    #pragma unroll
    for (int q = 0; q < 4; ++q) {
      const int kk = q >> 1, mh = q & 1;
      if (q == 0)      { if (t + 1 < nt) STG_A(t + 1, 1); }
      else if (q == 1) { if (t + 2 < nt) STG_B(t + 2, 0); }
      else if (q == 2) { if (t + 2 < nt) STG_A(t + 2, 0); }
      else             { if (t + 2 < nt) STG_B(t + 2, 1); }
      if (mh == 0) {
        const char* B1base = (const char*)&B1s[s][kk][0];
        const char* B3base = (const char*)&B3s[s][kk][0];
        #pragma unroll
        for (int n = 0; n < 2; ++n) {
          b1r[n] = *(const bf16x8*)(B1base + olB[n]);
          b3r[n] = *(const bf16x8*)(B3base + olB[n]);
        }
      }
      const char* Abase = (const char*)&As[s][kk][0];
      bf16x8 af[4];
      #pragma unroll
      for (int j = 0; j < 4; ++j)
        af[j] = *(const bf16x8*)(Abase + olA[mh][j]);
      PHASE_MFMA_OPEN();
      #pragma unroll
      for (int j = 0; j < 4; ++j) {
        #pragma unroll
        for (int n = 0; n < 2; ++n) {
          acc1[mh * 4 + j][n] =
            __builtin_amdgcn_mfma_f32_16x16x32_bf16(af[j], b1r[n], acc1[mh * 4 + j][n], 0, 0, 0);
          acc3[mh * 4 + j][n] =
            __builtin_amdgcn_mfma_f32_16x16x32_bf16(af[j], b3r[n], acc3[mh * 4 + j][n], 0, 0, 0);
        }
      }
      PHASE_MFMA_CLOSE();
      if (q == 3) asm volatile("s_waitcnt vmcnt(6)" ::: "memory");
      block_sync();
    }
  }
#undef STG_A
#undef STG_B

  #pragma unroll
  for (int m = 0; m < 8; ++m) {
    const int rb = wm * 128 + m * 16 + fg * 4;
    #pragma unroll
    for (int n = 0; n < 2; ++n) {
      const int cg = tn + wn * 32 + n * 16 + fr;
      #pragma unroll
      for (int j = 0; j < 4; ++j) {
        const int r = tm + rb + j;
        const float f1 = acc1[m][n][j];
        const float f3 = acc3[m][n][j];
        const float sg = f1 / (1.0f + __expf(-f1));
        G[(size_t)r * 3072 + cg] = (bf16_t)(sg * f3);
      }
    }
  }
}

// ---------------------------------------------------------------------------
// Dual k/v projection: shared A staging, two B operands. 128x128, BK=64.
// ---------------------------------------------------------------------------
__global__ __launch_bounds__(256) void gemm_kv(
    const bf16_t* __restrict__ A, const bf16_t* __restrict__ Bk,
    const bf16_t* __restrict__ Bv, bf16_t* __restrict__ kout,
    bf16_t* __restrict__ vout, const float* __restrict__ bias,
    int M, int N, int K)
{
  __shared__ bf16_t Asl[128 * 64];
  __shared__ bf16_t Bks[128 * 64];
  __shared__ bf16_t Bvs[128 * 64];
  const int tid  = threadIdx.x;
  const int lane = tid & 63;
  const int wid  = tid >> 6;
  const int tm = blockIdx.y * 128;
  const int tn = blockIdx.x * 128;
  const int row0 = (wid & 1) * 64;
  const int col0 = (wid >> 1) * 64;
  const int fr = lane & 15;
  const int fg = lane >> 4;

  f32x4 acck[4][4] = {};
  f32x4 accv[4][4] = {};

  for (int k0 = 0; k0 < K; k0 += 64) {
    #pragma unroll
    for (int i = 0; i < 4; ++i) {
      const int ebase = (i * 4 + wid) * 512;
      const int e0 = ebase + lane * 8;
      const int r  = e0 >> 6;
      const int c  = e0 & 63;
      gl_lds16(A  + (size_t)(tm + r) * K + (k0 + c), &Asl[ebase]);
      gl_lds16(Bk + (size_t)(tn + r) * K + (k0 + c), &Bks[ebase]);
      gl_lds16(Bv + (size_t)(tn + r) * K + (k0 + c), &Bvs[ebase]);
    }
    __syncthreads();

    #pragma unroll
    for (int kk = 0; kk < 2; ++kk) {
      bf16x8 af[4], bk[4], bv2[4];
      #pragma unroll
      for (int m = 0; m < 4; ++m)
        af[m] = *(const bf16x8*)&Asl[(row0 + m * 16 + fr) * 64 + kk * 32 + fg * 8];
      #pragma unroll
      for (int n = 0; n < 4; ++n) {
        bk[n]  = *(const bf16x8*)&Bks[(col0 + n * 16 + fr) * 64 + kk * 32 + fg * 8];
        bv2[n] = *(const bf16x8*)&Bvs[(col0 + n * 16 + fr) * 64 + kk * 32 + fg * 8];
      }
      #pragma unroll
      for (int m = 0; m < 4; ++m) {
        #pragma unroll
        for (int n = 0; n < 4; ++n) {
          acck[m][n] = __builtin_amdgcn_mfma_f32_16x16x32_bf16(af[m], bk[n],  acck[m][n], 0, 0, 0);
          accv[m][n] = __builtin_amdgcn_mfma_f32_16x16x32_bf16(af[m], bv2[n], accv[m][n], 0, 0, 0);
        }
      }
    }
    __syncthreads();
  }

  #pragma unroll
  for (int m = 0; m < 4; ++m) {
    const int rb = row0 + m * 16 + fg * 4;
    #pragma unroll
    for (int n = 0; n < 4; ++n) {
      const int cg = tn + col0 + n * 16 + fr;
      #pragma unroll
      for (int j = 0; j < 4; ++j) {
        const int r = tm + rb + j;
        kout[(size_t)r * N + cg] = (bf16_t)acck[m][n][j];
        vout[(size_t)r * N + cg] = (bf16_t)(accv[m][n][j] + bias[cg]);
      }
    }
  }
}

// ---------------------------------------------------------------------------
// 128x128 BK=64 GEMM (16x16x32) for small shapes. EPI 7 = bf16 transposed.
// ---------------------------------------------------------------------------
template <int EPI>
__global__ __launch_bounds__(256) void gemm_bt(
    const bf16_t* __restrict__ A, const bf16_t* __restrict__ B,
    void* outp, const void* auxp, int M, int N, int K)
{
  __shared__ bf16_t Asl[128 * 64];
  __shared__ bf16_t Bsl[128 * 64];
  const int tid  = threadIdx.x;
  const int lane = tid & 63;
  const int wid  = tid >> 6;
  const int tm = blockIdx.y * 128;
  const int tn = blockIdx.x * 128;
  const int row0 = (wid & 1) * 64;
  const int col0 = (wid >> 1) * 64;
  const int fr = lane & 15;
  const int fg = lane >> 4;

  f32x4 acc[4][4] = {};

  for (int k0 = 0; k0 < K; k0 += 64) {
    #pragma unroll
    for (int i = 0; i < 4; ++i) {
      const int ebase = (i * 4 + wid) * 512;
      const int e0 = ebase + lane * 8;
      const int r  = e0 >> 6;
      const int c  = e0 & 63;
      gl_lds16(A + (size_t)(tm + r) * K + (k0 + c), &Asl[ebase]);
      gl_lds16(B + (size_t)(tn + r) * K + (k0 + c), &Bsl[ebase]);
    }
    __syncthreads();

    #pragma unroll
    for (int kk = 0; kk < 2; ++kk) {
      bf16x8 af[4], bfv[4];
      #pragma unroll
      for (int m = 0; m < 4; ++m)
        af[m] = *(const bf16x8*)&Asl[(row0 + m * 16 + fr) * 64 + kk * 32 + fg * 8];
      #pragma unroll
      for (int n = 0; n < 4; ++n)
        bfv[n] = *(const bf16x8*)&Bsl[(col0 + n * 16 + fr) * 64 + kk * 32 + fg * 8];
      #pragma unroll
      for (int m = 0; m < 4; ++m) {
        #pragma unroll
        for (int n = 0; n < 4; ++n)
          acc[m][n] = __builtin_amdgcn_mfma_f32_16x16x32_bf16(af[m], bfv[n], acc[m][n], 0, 0, 0);
      }
    }
    __syncthreads();
  }

  #pragma unroll
  for (int m = 0; m < 4; ++m) {
    const int rb = row0 + m * 16 + fg * 4;
    #pragma unroll
    for (int n = 0; n < 4; ++n) {
      const int cg = tn + col0 + n * 16 + fr;
      #pragma unroll
      for (int j = 0; j < 4; ++j) {
        const int r = tm + rb + j;
        const float v = acc[m][n][j];
        if (EPI == 7) {
          ((bf16_t*)outp)[(size_t)cg * M + r] = (bf16_t)v;
        } else {
          ((bf16_t*)outp)[(size_t)r * N + cg] = (bf16_t)v;
        }
      }
    }
  }
}

// ---------------------------------------------------------------------------
__global__ __launch_bounds__(256) void rms_all(
    const float* __restrict__ cb, const float* __restrict__ lt,
    const float* __restrict__ ncs, const float* __restrict__ nqs,
    bf16_t* __restrict__ nc, bf16_t* __restrict__ nq)
{
  const int row = blockIdx.x, t = threadIdx.x;
  const float* xr;
  const float* scale;
  bf16_t* orow;
  if (row < 2048) {
    xr = cb + (size_t)row * 768; scale = ncs; orow = nc + (size_t)row * 768;
  } else {
    const int r2 = row - 2048;
    xr = lt + (size_t)r2 * 768; scale = nqs; orow = nq + (size_t)r2 * 768;
  }
  const float v0 = xr[t], v1 = xr[t + 256], v2 = xr[t + 512];
  float ss = v0 * v0 + v1 * v1 + v2 * v2;
  #pragma unroll
  for (int m = 32; m; m >>= 1) ss += __shfl_xor(ss, m);
  __shared__ float red[4];
  if ((t & 63) == 0) red[t >> 6] = ss;
  __syncthreads();
  const float tot = red[0] + red[1] + red[2] + red[3];
  const float inv = rsqrtf(tot / 768.0f + 1e-6f);
  orow[t]       = (bf16_t)(v0 * inv * scale[t]);
  orow[t + 256] = (bf16_t)(v1 * inv * scale[t + 256]);
  orow[t + 512] = (bf16_t)(v2 * inv * scale[t + 512]);
}

// ---------------------------------------------------------------------------
__global__ __launch_bounds__(256) void rms_rows(const float* __restrict__ x,
                                                const float* __restrict__ scale,
                                                bf16_t* __restrict__ out)
{
  const int row = blockIdx.x, t = threadIdx.x;
  const float* xr = x + (size_t)row * 768;
  const float v0 = xr[t], v1 = xr[t + 256], v2 = xr[t + 512];
  float ss = v0 * v0 + v1 * v1 + v2 * v2;
  #pragma unroll
  for (int m = 32; m; m >>= 1) ss += __shfl_xor(ss, m);
  __shared__ float red[4];
  if ((t & 63) == 0) red[t >> 6] = ss;
  __syncthreads();
  const float tot = red[0] + red[1] + red[2] + red[3];
  const float inv = rsqrtf(tot / 768.0f + 1e-6f);
  bf16_t* orow = out + (size_t)row * 768;
  orow[t]       = (bf16_t)(v0 * inv * scale[t]);
  orow[t + 256] = (bf16_t)(v1 * inv * scale[t + 256]);
  orow[t + 512] = (bf16_t)(v2 * inv * scale[t + 512]);
}

// ---------------------------------------------------------------------------
__global__ __launch_bounds__(128) void trig_fill(float* __restrict__ trig)
{
  const int p = blockIdx.x, t = threadIdx.x;
  #pragma unroll
  for (int j = 0; j < 3; ++j) {
    const int i = t + j * 128;
    const float invf = expf(-(float)i * (9.210340371976184f / 384.0f));
    const float ang  = (float)p * invf;
    trig[(size_t)p * 768 + i]       = cosf(ang);
    trig[(size_t)p * 768 + 384 + i] = sinf(ang);
  }
}

// ---------------------------------------------------------------------------
__global__ __launch_bounds__(128) void rope_qk(const bf16_t* __restrict__ qsrc,
                                               const bf16_t* __restrict__ ksrc,
                                               const int* __restrict__ pos,
                                               const float* __restrict__ trig,
                                               bf16_t* __restrict__ qdst,
                                               bf16_t* __restrict__ kdst)
{
  const int bid = blockIdx.x, t = threadIdx.x;
  const bf16_t* s;
  bf16_t* d;
  int p;
  if (bid < NROWS) {
    p = pos[bid];
    s = qsrc + (size_t)bid * 768;
    d = qdst + (size_t)bid * 768;
  } else {
    const int row = bid - NROWS;
    p = pos[row];
    s = ksrc + (size_t)(row & 2047) * 768;
    d = kdst + (size_t)row * 768;
  }
  const float* tr = trig + (size_t)p * 768;
  #pragma unroll
  for (int j = 0; j < 3; ++j) {
    const int i = t + j * 128;
    const float x1 = (float)s[i], x2 = (float)s[i + 384];
    const float c = tr[i], sn = tr[i + 384];
    d[i]       = (bf16_t)(x1 * c - x2 * sn);
    d[i + 384] = (bf16_t)(x1 * sn + x2 * c);
  }
}

// ---------------------------------------------------------------------------
__global__ __launch_bounds__(256) void softmax_g(const float* __restrict__ la,
                                                 float* __restrict__ lat,
                                                 float* __restrict__ z,
                                                 bf16_t* __restrict__ zb,
                                                 const float* __restrict__ taup,
                                                 const float* __restrict__ gnsp)
{
  const int row = blockIdx.x, t = threadIdx.x;
  const float tau = taup[0], gns = gnsp[0];
  const float* lar = la + (size_t)row * 2048;
  float* latr = lat + (size_t)row * 2048;
  float* zr   = z   + (size_t)row * 2048;
  bf16_t* zbr = zb  + (size_t)row * 2048;
  const uint32_t base = (uint32_t)row * 2048u;

  float vals[8];
  float mx = -3.0e38f;
  #pragma unroll
  for (int j = 0; j < 8; ++j) {
    const int c = t + j * 256;
    const uint32_t flat = base + (uint32_t)c;
    const uint2 rr = threefry2x32(0u, 42u, 0u, flat);
    const uint32_t bits = rr.x ^ rr.y;
    const float u = __uint_as_float((bits >> 9) | 0x3f800000u) - 1.0f;
    const float gum = -__logf(-__logf(u + 1e-10f) + 1e-10f);
    const float v = (lar[c] + gns * gum) / tau;
    vals[j] = v;
    latr[c] = v;
    mx = fmaxf(mx, v);
  }
  #pragma unroll
  for (int m = 32; m; m >>= 1) mx = fmaxf(mx, __shfl_xor(mx, m));
  __shared__ float redm[4];
  if ((t & 63) == 0) redm[t >> 6] = mx;
  __syncthreads();
  mx = fmaxf(fmaxf(redm[0], redm[1]), fmaxf(redm[2], redm[3]));

  float sum = 0.0f;
  #pragma unroll
  for (int j = 0; j < 8; ++j) { vals[j] = __expf(vals[j] - mx); sum += vals[j]; }
  #pragma unroll
  for (int m = 32; m; m >>= 1) sum += __shfl_xor(sum, m);
  __shared__ float reds[4];
  if ((t & 63) == 0) reds[t >> 6] = sum;
  __syncthreads();
  sum = reds[0] + reds[1] + reds[2] + reds[3];

  const float rinv = 1.0f / sum;
  #pragma unroll
  for (int j = 0; j < 8; ++j) {
    const int c = t + j * 256;
    const float zz = vals[j] * rinv;
    zr[c]  = zz;
    zbr[c] = (bf16_t)zz;
  }
}

// ---------------------------------------------------------------------------
__global__ __launch_bounds__(256) void convert_w(
    const float* __restrict__ wq, const float* __restrict__ wk,
    const float* __restrict__ wv, const float* __restrict__ wc,
    const float* __restrict__ w1, const float* __restrict__ w3,
    const float* __restrict__ w2, bf16_t* __restrict__ dst)
{
  const int idx = blockIdx.x * 256 + threadIdx.x;
  const float* src; int off;
  if      (idx < 589824)  { src = wq; off = 0; }
  else if (idx < 1179648) { src = wk; off = 589824; }
  else if (idx < 1769472) { src = wv; off = 1179648; }
  else if (idx < 2359296) { src = wc; off = 1769472; }
  else if (idx < 4718592) { src = w1; off = 2359296; }
  else if (idx < 7077888) { src = w3; off = 4718592; }
  else                    { src = w2; off = 7077888; }
  dst[idx] = (bf16_t)src[idx - off];
}

// ---------------------------------------------------------------------------
extern "C" void kernel_launch(void* const* d_in, const int* in_sizes, int n_in,
                              void* d_out, int out_size, void* d_ws, size_t ws_size,
                              hipStream_t stream)
{
  (void)in_sizes; (void)n_in; (void)out_size; (void)ws_size;
  const float* latents   = (const float*)d_in[0];
  const float* taup      = (const float*)d_in[1];
  const float* rsp       = (const float*)d_in[2];
  const float* gnsp      = (const float*)d_in[3];
  const int*   positions = (const int*)d_in[4];
  const float* codebook  = (const float*)d_in[5];
  const float* ncs       = (const float*)d_in[6];
  const float* nqs       = (const float*)d_in[7];
  const float* nfs       = (const float*)d_in[8];
  const float* Wq = (const float*)d_in[9];
  const float* Wk = (const float*)d_in[10];
  const float* Wv = (const float*)d_in[11];
  const float* bv = (const float*)d_in[12];
  const float* Wc = (const float*)d_in[13];
  const float* W1 = (const float*)d_in[14];
  const float* W2 = (const float*)d_in[15];
  const float* W3 = (const float*)d_in[16];

  char* ws = (char*)d_ws;
  char* ob = (char*)d_out;

  bf16_t* wbf  = (bf16_t*)(ws + WS_W);
  float*  trig = (float*)(ws + WS_TRIG);
  bf16_t* vcT  = (bf16_t*)(ws + WS_VCT);
  bf16_t* nc   = (bf16_t*)(ws + WS_NC);
  bf16_t* nq   = (bf16_t*)(ws + WS_NQ);
  bf16_t* zbuf = (bf16_t*)(ws + WS_Z);
  bf16_t* hbuf = (bf16_t*)(ws + WS_H);
  bf16_t* gbuf = (bf16_t*)(ws + WS_G);
  bf16_t* vbuf = (bf16_t*)(ws + WS_VB);

  float*  out_cb  = (float*)(ob + DO_CB);
  float*  out_la  = (float*)(ob + DO_LA);
  float*  out_lat = (float*)(ob + DO_LAT);
  float*  out_z   = (float*)(ob + DO_Z);
  bf16_t* qbase   = (bf16_t*)(ob + DO_QBASE);
  bf16_t* kbase   = (bf16_t*)(ob + DO_KBASE);
  bf16_t* qrope   = (bf16_t*)(ob + DO_QROPE);
  bf16_t* krope   = (bf16_t*)(ob + DO_KROPE);

  // P0: weight cast, merged norms, trig table
  convert_w<<<dim3(WTOT / 256), dim3(256), 0, stream>>>(Wq, Wk, Wv, Wc, W1, W3, W2, wbf);
  rms_all<<<dim3(C_ + NROWS), dim3(256), 0, stream>>>(codebook, latents, ncs, nqs, nc, nq);
  trig_fill<<<dim3(2048), dim3(128), 0, stream>>>(trig);

  // P1: projections. k,v in one dual-B kernel; vcT = (v@Wc^T)^T
  gemm_kv<<<dim3(6, 16), dim3(256), 0, stream>>>(nc, wbf + WK_OFF, wbf + WV_OFF,
                                                 kbase, vbuf, bv, C_, D_, D_);
  gemm_bt<7><<<dim3(6, 16), dim3(256), 0, stream>>>(vbuf, wbf + WC_OFF, vcT, nullptr, C_, D_, D_);
  gemm_n384<2><<<dim3(2, 128), dim3(512), 0, stream>>>(nq, wbf + WQ_OFF, qbase, nullptr, nullptr, D_);

  // P2: RoPE (q and k in one dispatch)
  rope_qk<<<dim3(2 * NROWS), dim3(128), 0, stream>>>(qbase, kbase, positions, trig, qrope, krope);

  // P3: log_alpha = q k^T / sqrt(D), batched over 8
  gemm8p<1><<<dim3(8, 8, 8), dim3(512), 0, stream>>>(qrope, krope, out_la, nullptr, nullptr,
                                                     N_, C_, D_, (long)N_ * D_, (long)C_ * D_, (long)N_ * C_);

  // P4: gumbel + log_alpha_tau + softmax z
  softmax_g<<<dim3(NROWS), dim3(256), 0, stream>>>(out_la, out_lat, out_z, zbuf, taup, gnsp);

  // P5: attn_output = rs*latents + z @ vc   (fused z@v@Wc^T, K=2048)
  gemm_n384<5><<<dim3(2, 128), dim3(512), 0, stream>>>(zbuf, vcT, out_cb, latents, rsp, C_);

  // P7: h = rms_norm(attn_output)
  rms_rows<<<dim3(NROWS), dim3(256), 0, stream>>>(out_cb, nfs, hbuf);

  // P8: FFN — fused up-projections, then down-projection
  gemm_ff13<<<dim3(24, 64), dim3(512), 0, stream>>>(hbuf, wbf + W1_OFF, wbf + W3_OFF, gbuf, D_);
  gemm_n384<6><<<dim3(2, 128), dim3(512), 0, stream>>>(gbuf, wbf + W2_OFF, out_cb, out_cb, nullptr, H_);
}